// Round 2
// baseline (135.933 us; speedup 1.0000x reference)
//
#include <hip/hip_runtime.h>
#include <hip/hip_bf16.h>

#define N 4096
#define IN_DIM 6
#define HID 32
#define HEADS1 4
#define D1 (HEADS1*HID)   // 128
#define OUT_DIM 64
#define MAXNB 192         // Binomial(4096,0.01): mean ~41, std 6.4 -> 192 is >20 sigma

// K1: hpre[i,t] = sum_k x[i,k]*W1[k,t]  (t = head*32+d), plus per-head e_src/e_dst dots.
// grid N, block 128
__global__ void k1_h1pre(const float* __restrict__ x,
                         const float* __restrict__ W1,
                         const float* __restrict__ a_src1,
                         const float* __restrict__ a_dst1,
                         float* __restrict__ hpre,
                         float* __restrict__ es1,
                         float* __restrict__ ed1) {
    int i = blockIdx.x;
    int t = threadIdx.x;           // 0..127
    __shared__ float xs[IN_DIM];
    if (t < IN_DIM) xs[t] = x[i*IN_DIM + t];
    __syncthreads();
    float acc = 0.f;
    #pragma unroll
    for (int k = 0; k < IN_DIM; ++k)
        acc += xs[k] * W1[k*D1 + t];
    hpre[(size_t)i*D1 + t] = acc;
    // e_src/e_dst: reduce over d (32 lanes per head). a_src1 is [4,32] flat = [128].
    float ps = acc * a_src1[t];
    float pd = acc * a_dst1[t];
    #pragma unroll
    for (int off = 16; off >= 1; off >>= 1) {   // xor offsets <32 stay inside each 32-lane head group
        ps += __shfl_xor(ps, off, 64);
        pd += __shfl_xor(pd, off, 64);
    }
    if ((t & 31) == 0) {
        int h = t >> 5;
        es1[i*HEADS1 + h] = ps;
        ed1[i*HEADS1 + h] = pd;
    }
}

// K2: CSR build. mask[i][j] = adj[i][j] > 0 || j == i. adj values are exactly 0.0f/1.0f.
// grid N, block 256. float4 = 4 elems per load, coalesced.
__global__ void k2_csr(const float* __restrict__ adj,
                       int* __restrict__ cnt, int* __restrict__ idxg) {
    int i = blockIdx.x;
    int t = threadIdx.x;
    __shared__ int c;
    __shared__ int list[MAXNB];
    if (t == 0) c = 0;
    __syncthreads();
    const float4* row = (const float4*)(adj + (size_t)i * N);   // 1024 float4 per row
    for (int k = t; k < N/4; k += 256) {
        float4 v = row[k];
        float f[4] = {v.x, v.y, v.z, v.w};
        #pragma unroll
        for (int q = 0; q < 4; ++q) {
            int j = k*4 + q;
            if (f[q] > 0.f || j == i) {
                int p = atomicAdd(&c, 1);
                if (p < MAXNB) list[p] = j;
            }
        }
    }
    __syncthreads();
    int cc = min(c, MAXNB);
    if (t == 0) cnt[i] = cc;
    for (int p = t; p < cc; p += 256) idxg[i*MAXNB + p] = list[p];
}

// K3: layer-1 masked softmax over neighbors + aggregate + bias + ELU.
// grid N, block 128 (thread t: head = t>>5, lane/d = t&31)
__global__ void k3_agg1(const float* __restrict__ hpre,
                        const float* __restrict__ es1,
                        const float* __restrict__ ed1,
                        const int* __restrict__ cnt,
                        const int* __restrict__ idxg,
                        const float* __restrict__ b1,
                        float* __restrict__ h1) {
    int i = blockIdx.x;
    int t = threadIdx.x;
    int c = cnt[i];                 // >=1 (self loop)
    __shared__ int js[MAXNB];
    __shared__ float alpha[HEADS1][MAXNB];
    __shared__ float esi[HEADS1];
    if (t < HEADS1) esi[t] = es1[i*HEADS1 + t];
    for (int p = t; p < c; p += 128) js[p] = idxg[i*MAXNB + p];
    __syncthreads();
    // logits (leaky_relu slope 0.2)
    for (int p = t; p < c; p += 128) {
        int j = js[p];
        #pragma unroll
        for (int h = 0; h < HEADS1; ++h) {
            float l = esi[h] + ed1[j*HEADS1 + h];
            alpha[h][p] = (l > 0.f) ? l : 0.2f*l;
        }
    }
    __syncthreads();
    int h = t >> 5, lane = t & 31;
    float m = -1e30f;
    for (int p = lane; p < c; p += 32) m = fmaxf(m, alpha[h][p]);
    #pragma unroll
    for (int off = 16; off >= 1; off >>= 1) m = fmaxf(m, __shfl_xor(m, off, 64));
    float s = 0.f;
    for (int p = lane; p < c; p += 32) s += __expf(alpha[h][p] - m);
    #pragma unroll
    for (int off = 16; off >= 1; off >>= 1) s += __shfl_xor(s, off, 64);
    float inv = 1.f / s;
    for (int p = lane; p < c; p += 32) alpha[h][p] = __expf(alpha[h][p] - m) * inv;
    __syncthreads();
    // aggregate: out[i,t] = sum_p alpha[h][p] * hpre[js[p]][t]
    float acc = 0.f;
    for (int p = 0; p < c; ++p)
        acc += alpha[h][p] * hpre[(size_t)js[p]*D1 + t];
    acc += b1[t];
    h1[(size_t)i*D1 + t] = (acc > 0.f) ? acc : expm1f(acc);   // ELU (alpha=1)
}

// K4: h2pre = h1 @ W2 ([128]->[64]) + e_src2/e_dst2 (1 head, d=64). grid N, block 64.
__global__ void k4_h2pre(const float* __restrict__ h1,
                         const float* __restrict__ W2,
                         const float* __restrict__ a_src2,
                         const float* __restrict__ a_dst2,
                         float* __restrict__ h2pre,
                         float* __restrict__ es2,
                         float* __restrict__ ed2) {
    int i = blockIdx.x;
    int t = threadIdx.x;            // 0..63
    __shared__ float hs[D1];
    hs[t]      = h1[(size_t)i*D1 + t];
    hs[t + 64] = h1[(size_t)i*D1 + t + 64];
    __syncthreads();
    float acc = 0.f;
    #pragma unroll
    for (int k = 0; k < D1; ++k)
        acc += hs[k] * W2[k*OUT_DIM + t];
    h2pre[(size_t)i*OUT_DIM + t] = acc;
    float ps = acc * a_src2[t];
    float pd = acc * a_dst2[t];
    #pragma unroll
    for (int off = 32; off >= 1; off >>= 1) {
        ps += __shfl_xor(ps, off, 64);
        pd += __shfl_xor(pd, off, 64);
    }
    if (t == 0) { es2[i] = ps; ed2[i] = pd; }
}

// K5: layer-2 masked softmax + aggregate + bias -> fp32 out. grid N, block 64 (1 wave).
__global__ void k5_agg2(const float* __restrict__ h2pre,
                        const float* __restrict__ es2,
                        const float* __restrict__ ed2,
                        const int* __restrict__ cnt,
                        const int* __restrict__ idxg,
                        const float* __restrict__ b2v,
                        float* __restrict__ out) {
    int i = blockIdx.x;
    int t = threadIdx.x;            // 0..63
    int c = cnt[i];
    __shared__ int js[MAXNB];
    __shared__ float alpha[MAXNB];
    for (int p = t; p < c; p += 64) js[p] = idxg[i*MAXNB + p];
    __syncthreads();
    float esi = es2[i];
    float m = -1e30f;
    for (int p = t; p < c; p += 64) {
        float l = esi + ed2[js[p]];
        l = (l > 0.f) ? l : 0.2f*l;
        alpha[p] = l;
        m = fmaxf(m, l);
    }
    #pragma unroll
    for (int off = 32; off >= 1; off >>= 1) m = fmaxf(m, __shfl_xor(m, off, 64));
    __syncthreads();
    float s = 0.f;
    for (int p = t; p < c; p += 64) s += __expf(alpha[p] - m);
    #pragma unroll
    for (int off = 32; off >= 1; off >>= 1) s += __shfl_xor(s, off, 64);
    float inv = 1.f / s;
    for (int p = t; p < c; p += 64) alpha[p] = __expf(alpha[p] - m) * inv;
    __syncthreads();
    float acc = 0.f;
    for (int p = 0; p < c; ++p)
        acc += alpha[p] * h2pre[(size_t)js[p]*OUT_DIM + t];
    acc += b2v[t];
    out[(size_t)i*OUT_DIM + t] = acc;
}

extern "C" void kernel_launch(void* const* d_in, const int* in_sizes, int n_in,
                              void* d_out, int out_size, void* d_ws, size_t ws_size,
                              hipStream_t stream) {
    const float* x      = (const float*)d_in[0];
    const float* adj    = (const float*)d_in[1];
    const float* W1     = (const float*)d_in[2];
    const float* a_src1 = (const float*)d_in[3];
    const float* a_dst1 = (const float*)d_in[4];
    const float* b1     = (const float*)d_in[5];
    const float* W2     = (const float*)d_in[6];
    const float* a_src2 = (const float*)d_in[7];
    const float* a_dst2 = (const float*)d_in[8];
    const float* b2v    = (const float*)d_in[9];
    float* out = (float*)d_out;

    // workspace layout (fp32 words), ~8.6 MB total
    float* ws    = (float*)d_ws;
    float* hpre  = ws;                       // N*128
    float* h1    = hpre  + (size_t)N*D1;     // N*128
    float* h2pre = h1    + (size_t)N*D1;     // N*64
    float* es1   = h2pre + (size_t)N*OUT_DIM;// N*4
    float* ed1   = es1   + (size_t)N*HEADS1; // N*4
    float* es2   = ed1   + (size_t)N*HEADS1; // N
    float* ed2   = es2   + N;                // N
    int*   cnt   = (int*)(ed2 + N);          // N
    int*   idxg  = cnt + N;                  // N*MAXNB

    k1_h1pre<<<N, 128, 0, stream>>>(x, W1, a_src1, a_dst1, hpre, es1, ed1);
    k2_csr  <<<N, 256, 0, stream>>>(adj, cnt, idxg);
    k3_agg1 <<<N, 128, 0, stream>>>(hpre, es1, ed1, cnt, idxg, b1, h1);
    k4_h2pre<<<N,  64, 0, stream>>>(h1, W2, a_src2, a_dst2, h2pre, es2, ed2);
    k5_agg2 <<<N,  64, 0, stream>>>(h2pre, es2, ed2, cnt, idxg, b2v, out);
}